// Round 1
// baseline (1490.214 us; speedup 1.0000x reference)
//
#include <hip/hip_runtime.h>

#define HW 1024
#define TWO_PI_F 6.28318530717958647692f

__device__ __forceinline__ float2 cmulf(float2 a, float2 b){
  return make_float2(a.x*b.x - a.y*b.y, a.x*b.y + a.y*b.x);
}

// 256-thread block reduction of a double (4 waves of 64)
__device__ __forceinline__ double block_reduce_add(double v, double* sc){
  int tid = threadIdx.x;
  #pragma unroll
  for (int o = 32; o > 0; o >>= 1) v += __shfl_down(v, o, 64);
  __syncthreads();                 // protect sc reuse across successive calls
  if ((tid & 63) == 0) sc[tid >> 6] = v;
  __syncthreads();
  return sc[0] + sc[1] + sc[2] + sc[3];
}

__global__ void zero_acc_kernel(double* acc){
  if (threadIdx.x < 8) acc[threadIdx.x] = 0.0;
}

// ---------------------------------------------------------------------------
// Spatial half: grad/dir/curv losses (3 boundary widths), smoothness, slope
// continuity. One 16x16 output tile per block, halo 3. Accumulates 3 sums.
// acc[0]=grad numerator, acc[1]=smooth, acc[2]=slope
// ---------------------------------------------------------------------------
__global__ __launch_bounds__(256)
void spatial_kernel(const float* __restrict__ pred, const float* __restrict__ targ,
                    const float* __restrict__ mask, double* __restrict__ acc){
  __shared__ float sp[20*21];   // pred, halo 2, padded stride 21
  __shared__ float st[20*21];   // target
  __shared__ float smk[22*23];  // mask, halo 3, stride 23
  __shared__ float pmg[18*19];  // pred grad magnitude, halo 1, stride 19
  __shared__ float tmg[18*19];  // target grad magnitude
  __shared__ double sc[4];

  const int tid = threadIdx.x;
  const int x0 = blockIdx.x << 4, y0 = blockIdx.y << 4;
  const size_t ib = (size_t)blockIdx.z * ((size_t)HW * HW);

  // load pred/target with halo 2 (zero outside image)
  for (int i = tid; i < 400; i += 256){
    int a = i / 20, b = i % 20;
    int gy = y0 - 2 + a, gx = x0 - 2 + b;
    float pv = 0.f, tv = 0.f;
    if ((unsigned)gy < HW && (unsigned)gx < HW){
      size_t idx = ib + (size_t)gy * HW + gx;
      pv = pred[idx]; tv = targ[idx];
    }
    sp[a*21+b] = pv; st[a*21+b] = tv;
  }
  // load mask with halo 3
  for (int i = tid; i < 484; i += 256){
    int a = i / 22, b = i % 22;
    int gy = y0 - 3 + a, gx = x0 - 3 + b;
    float v = 0.f;
    if ((unsigned)gy < HW && (unsigned)gx < HW) v = mask[ib + (size_t)gy * HW + gx];
    smk[a*23+b] = v;
  }
  __syncthreads();

  // gradient magnitude over halo-1 region (zero OUTSIDE image: conv zero-pads
  // p_mag itself, so OOB entries must be exactly 0, not sqrt(1e-8))
  for (int i = tid; i < 324; i += 256){
    int iy = i / 18, ix = i % 18;
    int gy = y0 - 1 + iy, gx = x0 - 1 + ix;
    float pv = 0.f, tv = 0.f;
    if ((unsigned)gy < HW && (unsigned)gx < HW){
      float a00=sp[(iy  )*21+ix], a01=sp[(iy  )*21+ix+1], a02=sp[(iy  )*21+ix+2];
      float a10=sp[(iy+1)*21+ix],                          a12=sp[(iy+1)*21+ix+2];
      float a20=sp[(iy+2)*21+ix], a21=sp[(iy+2)*21+ix+1], a22=sp[(iy+2)*21+ix+2];
      float a01b=sp[(iy)*21+ix+1]; (void)a01b;
      float gxp = (a02 + 2.f*a12 + a22) - (a00 + 2.f*a10 + a20);
      float gyp = (a20 + 2.f*a21 + a22) - (a00 + 2.f*a01 + a02);
      pv = sqrtf(gxp*gxp + gyp*gyp + 1e-8f);
      float b00=st[(iy  )*21+ix], b01=st[(iy  )*21+ix+1], b02=st[(iy  )*21+ix+2];
      float b10=st[(iy+1)*21+ix],                          b12=st[(iy+1)*21+ix+2];
      float b20=st[(iy+2)*21+ix], b21=st[(iy+2)*21+ix+1], b22=st[(iy+2)*21+ix+2];
      float gxt = (b02 + 2.f*b12 + b22) - (b00 + 2.f*b10 + b20);
      float gyt = (b20 + 2.f*b21 + b22) - (b00 + 2.f*b01 + b02);
      tv = sqrtf(gxt*gxt + gyt*gyt + 1e-8f);
    }
    pmg[iy*19+ix] = pv; tmg[iy*19+ix] = tv;
  }
  __syncthreads();

  // per-pixel losses (all 256 center pixels in-bounds: 1024 % 16 == 0)
  const int ty = tid >> 4, tx = tid & 15;

  float p[3][3], q[3][3];
  #pragma unroll
  for (int r = 0; r < 3; r++)
    #pragma unroll
    for (int c = 0; c < 3; c++){
      p[r][c] = sp[(ty+1+r)*21 + (tx+1+c)];
      q[r][c] = st[(ty+1+r)*21 + (tx+1+c)];
    }
  float gxp = (p[0][2]+2.f*p[1][2]+p[2][2]) - (p[0][0]+2.f*p[1][0]+p[2][0]);
  float gyp = (p[2][0]+2.f*p[2][1]+p[2][2]) - (p[0][0]+2.f*p[0][1]+p[0][2]);
  float cvp = 4.f*p[1][1] - p[0][1] - p[1][0] - p[1][2] - p[2][1];
  float gxt = (q[0][2]+2.f*q[1][2]+q[2][2]) - (q[0][0]+2.f*q[1][0]+q[2][0]);
  float gyt = (q[2][0]+2.f*q[2][1]+q[2][2]) - (q[0][0]+2.f*q[0][1]+q[0][2]);
  float cvt = 4.f*q[1][1] - q[0][1] - q[1][0] - q[1][2] - q[2][1];

  float pmagc = pmg[(ty+1)*19 + tx+1];
  float tmagc = tmg[(ty+1)*19 + tx+1];
  float dirp = atan2f(gyp, gxp + 1e-8f);
  float dirt = atan2f(gyt, gxt + 1e-8f);
  float sd = fabsf(pmagc - tmagc);
  float dd = fabsf(dirp - dirt); dd = fminf(dd, TWO_PI_F - dd);
  float cd = fabsf(cvp - cvt);

  // boundary masks via incremental ring sums (mask entries are exact 0/1)
  const int cy = ty + 3, cx = tx + 3;
  float s1 = 0.f;
  #pragma unroll
  for (int dy = -1; dy <= 1; dy++)
    #pragma unroll
    for (int dx = -1; dx <= 1; dx++) s1 += smk[(cy+dy)*23 + cx+dx];
  float s2 = s1;
  #pragma unroll
  for (int d = -2; d <= 2; d++) s2 += smk[(cy-2)*23 + cx+d] + smk[(cy+2)*23 + cx+d];
  #pragma unroll
  for (int d = -1; d <= 1; d++) s2 += smk[(cy+d)*23 + cx-2] + smk[(cy+d)*23 + cx+2];
  float s3 = s2;
  #pragma unroll
  for (int d = -3; d <= 3; d++) s3 += smk[(cy-3)*23 + cx+d] + smk[(cy+3)*23 + cx+d];
  #pragma unroll
  for (int d = -2; d <= 2; d++) s3 += smk[(cy+d)*23 + cx-3] + smk[(cy+d)*23 + cx+3];

  float w1 = (s1 > 0.5f && s1 <  8.5f) ? 1.f : 0.f;
  float w2 = (s2 > 0.5f && s2 < 24.5f) ? 1.f : 0.f;
  float w3 = (s3 > 0.5f && s3 < 48.5f) ? 1.f : 0.f;

  // grad loss numerator: weights (1,2) for w1, (0.5,1) for w2/w3
  float gc = (sd + dd) * (w1 + 0.5f*(w2 + w3)) + cd * (2.f*w1 + w2 + w3);

  // smoothness: local std of pred over 3x3 box
  float s9 = 0.f, s9q = 0.f;
  #pragma unroll
  for (int r = 0; r < 3; r++)
    #pragma unroll
    for (int c = 0; c < 3; c++){ s9 += p[r][c]; s9q += p[r][c]*p[r][c]; }
  float lm = s9 * (1.f/9.f), lq = s9q * (1.f/9.f);
  float var = fmaxf(lq - lm*lm, 1e-8f);
  float smc = sqrtf(var) * w1;

  // slope continuity: Sobel of grad-magnitude fields
  float am[3][3], bm[3][3];
  #pragma unroll
  for (int r = 0; r < 3; r++)
    #pragma unroll
    for (int c = 0; c < 3; c++){
      am[r][c] = pmg[(ty+r)*19 + tx+c];
      bm[r][c] = tmg[(ty+r)*19 + tx+c];
    }
  float psx = (am[0][2]+2.f*am[1][2]+am[2][2]) - (am[0][0]+2.f*am[1][0]+am[2][0]);
  float psy = (am[2][0]+2.f*am[2][1]+am[2][2]) - (am[0][0]+2.f*am[0][1]+am[0][2]);
  float pch = sqrtf(psx*psx + psy*psy + 1e-8f);
  float tsx = (bm[0][2]+2.f*bm[1][2]+bm[2][2]) - (bm[0][0]+2.f*bm[1][0]+bm[2][0]);
  float tsy = (bm[2][0]+2.f*bm[2][1]+bm[2][2]) - (bm[0][0]+2.f*bm[0][1]+bm[0][2]);
  float tch = sqrtf(tsx*tsx + tsy*tsy + 1e-8f);
  float slc = fabsf(pch - tch) * w1;

  double g  = block_reduce_add((double)gc,  sc);
  double sm = block_reduce_add((double)smc, sc);
  double sl = block_reduce_add((double)slc, sc);
  if (tid == 0){
    atomicAdd(&acc[0], g);
    atomicAdd(&acc[1], sm);
    atomicAdd(&acc[2], sl);
  }
}

// ---------------------------------------------------------------------------
// FFT pass 1: per-row 1024-pt complex FFT of z = pred + i*target, in ws
// ---------------------------------------------------------------------------
__global__ __launch_bounds__(256)
void fft_rows_kernel(const float* __restrict__ pred, const float* __restrict__ targ,
                     float2* __restrict__ Z, int img0){
  __shared__ float2 buf[1024];
  __shared__ float2 tw[512];
  const int tid = threadIdx.x;
  const int row = blockIdx.x;
  const size_t ibase = ((size_t)(img0 + blockIdx.y) * HW + row) * HW;
  float2* zrow = Z + ((size_t)blockIdx.y * HW + row) * HW;

  for (int i = tid; i < 512; i += 256){
    float s, c; sincosf(-TWO_PI_F * (float)i * (1.f/1024.f), &s, &c);
    tw[i] = make_float2(c, s);
  }
  #pragma unroll
  for (int j = 0; j < 4; j++){
    int e = tid + (j << 8);
    int r = __brev(e) >> 22;          // bit-reversed load
    buf[r] = make_float2(pred[ibase + e], targ[ibase + e]);
  }
  __syncthreads();
  for (int s = 0; s < 10; s++){
    int half = 1 << s;
    #pragma unroll
    for (int j = 0; j < 2; j++){
      int b = tid + (j << 8);
      int grp = b >> s;
      int pos = b & (half - 1);
      int i0 = (grp << (s+1)) + pos, i1 = i0 + half;
      float2 w = tw[pos << (9 - s)];
      float2 u = buf[i0], v = buf[i1];
      float2 t = cmulf(w, v);
      buf[i0] = make_float2(u.x + t.x, u.y + t.y);
      buf[i1] = make_float2(u.x - t.x, u.y - t.y);
    }
    __syncthreads();
  }
  #pragma unroll
  for (int j = 0; j < 4; j++){
    int e = tid + (j << 8);
    zrow[e] = buf[e];
  }
}

// ---------------------------------------------------------------------------
// In-place square transpose via 32x32 tile pairs
// ---------------------------------------------------------------------------
__global__ __launch_bounds__(256)
void transpose_kernel(float2* __restrict__ Z){
  const int ti = blockIdx.y, tj = blockIdx.x;
  if (tj < ti) return;                       // uniform early-exit (no barriers yet)
  __shared__ float2 A[32*33];
  __shared__ float2 B[32*33];
  float2* base = Z + (size_t)blockIdx.z * HW * HW;
  const int tx = threadIdx.x & 31, ty = threadIdx.x >> 5;   // ty in [0,8)
  const bool off = (ti != tj);
  #pragma unroll
  for (int k = 0; k < 4; k++){
    int r = ty + (k << 3);
    A[r*33+tx] = base[(size_t)(ti*32+r)*HW + tj*32+tx];
    if (off) B[r*33+tx] = base[(size_t)(tj*32+r)*HW + ti*32+tx];
  }
  __syncthreads();
  #pragma unroll
  for (int k = 0; k < 4; k++){
    int r = ty + (k << 3);
    base[(size_t)(tj*32+r)*HW + ti*32+tx] = A[tx*33+r];
    if (off) base[(size_t)(ti*32+r)*HW + tj*32+tx] = B[tx*33+r];
  }
}

// ---------------------------------------------------------------------------
// FFT pass 2 + frequency reduce. After transpose, Zt(a,y) = rowFFT(y,a).
// FFT of Zt row a gives G(a,k) = F(k, a) (bins k2 = a, all k1).
// Partner row ap = (-a) mod 1024 supplies Z(-k) for the Hermitian unpack:
//   pf = (Z(k)+conj(Z(-k)))/2 ; tf = (Z(k)-conj(Z(-k)))/(2i)
// acc[3] += hf*(|pf|-|tf|)^2 ; acc[4] += hf*wrap(ph_p-ph_t)^2
// ---------------------------------------------------------------------------
__device__ __forceinline__ void freq_contrib(float2 Zk, float2 Zm, int k1, int k2,
                                             double& ms, double& ps){
  int di = k1 - 512, dj = k2 - 512;
  if (di*di + dj*dj < 94372) return;         // dist > 307.2  <=>  r2 >= 94372
  float pr = 0.5f*(Zk.x + Zm.x);
  float pi = 0.5f*(Zk.y - Zm.y);
  float tr = 0.5f*(Zk.y + Zm.y);
  float ti = 0.5f*(Zm.x - Zk.x);
  float pmv = sqrtf(pr*pr + pi*pi);
  float tmv = sqrtf(tr*tr + ti*ti);
  float dm = pmv - tmv;
  ms += (double)(dm*dm);
  float re = pr*tr + pi*ti;                  // Re(pf * conj(tf))
  float im = pi*tr - pr*ti;                  // Im(pf * conj(tf))
  float pd = atan2f(im, re);                 // wrapped phase difference
  ps += (double)(pd*pd);
}

__global__ __launch_bounds__(256)
void fft_cols_reduce_kernel(const float2* __restrict__ Z, double* __restrict__ acc){
  __shared__ float2 b1[1024];
  __shared__ float2 b2[1024];
  __shared__ float2 tw[512];
  __shared__ double sc[4];
  const int tid = threadIdx.x;
  const int a  = blockIdx.x;                 // 0..512
  const int ap = (1024 - a) & 1023;
  const float2* base = Z + (size_t)blockIdx.y * HW * HW;

  for (int i = tid; i < 512; i += 256){
    float s, c; sincosf(-TWO_PI_F * (float)i * (1.f/1024.f), &s, &c);
    tw[i] = make_float2(c, s);
  }
  #pragma unroll
  for (int j = 0; j < 4; j++){
    int e = tid + (j << 8);
    int r = __brev(e) >> 22;
    b1[r] = base[(size_t)a  * HW + e];
    b2[r] = base[(size_t)ap * HW + e];
  }
  __syncthreads();
  for (int s = 0; s < 10; s++){
    int half = 1 << s;
    #pragma unroll
    for (int j = 0; j < 2; j++){
      int b = tid + (j << 8);
      int grp = b >> s;
      int pos = b & (half - 1);
      int i0 = (grp << (s+1)) + pos, i1 = i0 + half;
      float2 w = tw[pos << (9 - s)];
      float2 u = b1[i0], v = b1[i1];
      float2 t = cmulf(w, v);
      b1[i0] = make_float2(u.x + t.x, u.y + t.y);
      b1[i1] = make_float2(u.x - t.x, u.y - t.y);
      u = b2[i0]; v = b2[i1];
      t = cmulf(w, v);
      b2[i0] = make_float2(u.x + t.x, u.y + t.y);
      b2[i1] = make_float2(u.x - t.x, u.y - t.y);
    }
    __syncthreads();
  }

  double ms = 0.0, ps = 0.0;
  const bool two = (a != ap);                // self-paired rows 0 and 512
  #pragma unroll
  for (int j = 0; j < 4; j++){
    int k  = tid + (j << 8);
    int km = (1024 - k) & 1023;
    freq_contrib(b1[k], b2[km], k, a, ms, ps);
    if (two) freq_contrib(b2[k], b1[km], k, ap, ms, ps);
  }
  ms = block_reduce_add(ms, sc);
  ps = block_reduce_add(ps, sc);
  if (tid == 0){
    atomicAdd(&acc[3], ms);
    atomicAdd(&acc[4], ps);
  }
}

// ---------------------------------------------------------------------------
__global__ void finalize_kernel(const double* __restrict__ acc, float* __restrict__ out){
  if (threadIdx.x == 0 && blockIdx.x == 0){
    const double inv = 1.0 / 8388608.0;      // mean over 8*1024*1024
    double grad   = acc[0] * inv / 3.0;      // / len(bms)
    double smooth = acc[1] * inv;
    double slope  = acc[2] * inv;
    double freq   = (acc[3] + 2.0 * acc[4]) * inv;
    double total  = 2.0*grad + 1.5*freq + 3.0*smooth + 2.0*slope;
    out[0] = (float)total;
    out[1] = (float)grad;
    out[2] = (float)freq;
    out[3] = (float)smooth;
    out[4] = (float)slope;
  }
}

extern "C" void kernel_launch(void* const* d_in, const int* in_sizes, int n_in,
                              void* d_out, int out_size, void* d_ws, size_t ws_size,
                              hipStream_t stream){
  const float* pred = (const float*)d_in[0];
  const float* targ = (const float*)d_in[1];
  const float* mask = (const float*)d_in[2];
  double* acc = (double*)d_ws;
  float2* Z = (float2*)((char*)d_ws + 256);
  const size_t zimg = (size_t)HW * HW * sizeof(float2);   // 8 MiB per image

  int cmax = 1;
  if (ws_size > 256){
    size_t c = (ws_size - 256) / zimg;
    if (c > 8) c = 8;
    if (c < 1) c = 1;
    cmax = (int)c;
  }

  zero_acc_kernel<<<1, 64, 0, stream>>>(acc);
  spatial_kernel<<<dim3(64, 64, 8), 256, 0, stream>>>(pred, targ, mask, acc);
  for (int i0 = 0; i0 < 8; i0 += cmax){
    int c = (8 - i0 < cmax) ? (8 - i0) : cmax;
    fft_rows_kernel<<<dim3(1024, c), 256, 0, stream>>>(pred, targ, Z, i0);
    transpose_kernel<<<dim3(32, 32, c), 256, 0, stream>>>(Z);
    fft_cols_reduce_kernel<<<dim3(513, c), 256, 0, stream>>>(Z, acc);
  }
  finalize_kernel<<<1, 64, 0, stream>>>(acc, (float*)d_out);
}

// Round 2
// 394.201 us; speedup vs baseline: 3.7803x; 3.7803x over previous
//
#include <hip/hip_runtime.h>

#define HW 1024
#define TWO_PI_F 6.28318530717958647692f
#define NSLOT 64   // atomic spreading: 64 slots per accumulator, 5 accumulators

__device__ __forceinline__ float2 cmulf(float2 a, float2 b){
  return make_float2(a.x*b.x - a.y*b.y, a.x*b.y + a.y*b.x);
}

// 256-thread block reduction of a double (4 waves of 64)
__device__ __forceinline__ double block_reduce_add(double v, double* sc){
  int tid = threadIdx.x;
  #pragma unroll
  for (int o = 32; o > 0; o >>= 1) v += __shfl_down(v, o, 64);
  __syncthreads();                 // protect sc reuse across successive calls
  if ((tid & 63) == 0) sc[tid >> 6] = v;
  __syncthreads();
  return sc[0] + sc[1] + sc[2] + sc[3];
}

__global__ void zero_acc_kernel(double* acc){
  int i = threadIdx.x + blockIdx.x * blockDim.x;
  if (i < 5 * NSLOT) acc[i] = 0.0;
}

// ---------------------------------------------------------------------------
// Spatial half: grad/dir/curv losses (3 boundary widths), smoothness, slope
// continuity. One 16x16 output tile per block, halo 3. Accumulates 3 sums.
// acc rows: 0=grad numerator, 1=smooth, 2=slope (each NSLOT wide)
// ---------------------------------------------------------------------------
__global__ __launch_bounds__(256)
void spatial_kernel(const float* __restrict__ pred, const float* __restrict__ targ,
                    const float* __restrict__ mask, double* __restrict__ acc){
  __shared__ float sp[20*21];   // pred, halo 2, padded stride 21
  __shared__ float st[20*21];   // target
  __shared__ float smk[22*23];  // mask, halo 3, stride 23
  __shared__ float pmg[18*19];  // pred grad magnitude, halo 1, stride 19
  __shared__ float tmg[18*19];  // target grad magnitude
  __shared__ double sc[4];

  const int tid = threadIdx.x;
  const int x0 = blockIdx.x << 4, y0 = blockIdx.y << 4;
  const size_t ib = (size_t)blockIdx.z * ((size_t)HW * HW);

  // load pred/target with halo 2 (zero outside image)
  for (int i = tid; i < 400; i += 256){
    int a = i / 20, b = i % 20;
    int gy = y0 - 2 + a, gx = x0 - 2 + b;
    float pv = 0.f, tv = 0.f;
    if ((unsigned)gy < HW && (unsigned)gx < HW){
      size_t idx = ib + (size_t)gy * HW + gx;
      pv = pred[idx]; tv = targ[idx];
    }
    sp[a*21+b] = pv; st[a*21+b] = tv;
  }
  // load mask with halo 3
  for (int i = tid; i < 484; i += 256){
    int a = i / 22, b = i % 22;
    int gy = y0 - 3 + a, gx = x0 - 3 + b;
    float v = 0.f;
    if ((unsigned)gy < HW && (unsigned)gx < HW) v = mask[ib + (size_t)gy * HW + gx];
    smk[a*23+b] = v;
  }
  __syncthreads();

  // gradient magnitude over halo-1 region (zero OUTSIDE image: conv zero-pads
  // p_mag itself, so OOB entries must be exactly 0, not sqrt(1e-8))
  for (int i = tid; i < 324; i += 256){
    int iy = i / 18, ix = i % 18;
    int gy = y0 - 1 + iy, gx = x0 - 1 + ix;
    float pv = 0.f, tv = 0.f;
    if ((unsigned)gy < HW && (unsigned)gx < HW){
      float a00=sp[(iy  )*21+ix], a01=sp[(iy  )*21+ix+1], a02=sp[(iy  )*21+ix+2];
      float a10=sp[(iy+1)*21+ix],                          a12=sp[(iy+1)*21+ix+2];
      float a20=sp[(iy+2)*21+ix], a21=sp[(iy+2)*21+ix+1], a22=sp[(iy+2)*21+ix+2];
      float gxp = (a02 + 2.f*a12 + a22) - (a00 + 2.f*a10 + a20);
      float gyp = (a20 + 2.f*a21 + a22) - (a00 + 2.f*a01 + a02);
      pv = sqrtf(gxp*gxp + gyp*gyp + 1e-8f);
      float b00=st[(iy  )*21+ix], b01=st[(iy  )*21+ix+1], b02=st[(iy  )*21+ix+2];
      float b10=st[(iy+1)*21+ix],                          b12=st[(iy+1)*21+ix+2];
      float b20=st[(iy+2)*21+ix], b21=st[(iy+2)*21+ix+1], b22=st[(iy+2)*21+ix+2];
      float gxt = (b02 + 2.f*b12 + b22) - (b00 + 2.f*b10 + b20);
      float gyt = (b20 + 2.f*b21 + b22) - (b00 + 2.f*b01 + b02);
      tv = sqrtf(gxt*gxt + gyt*gyt + 1e-8f);
    }
    pmg[iy*19+ix] = pv; tmg[iy*19+ix] = tv;
  }
  __syncthreads();

  // per-pixel losses (all 256 center pixels in-bounds: 1024 % 16 == 0)
  const int ty = tid >> 4, tx = tid & 15;

  float p[3][3], q[3][3];
  #pragma unroll
  for (int r = 0; r < 3; r++)
    #pragma unroll
    for (int c = 0; c < 3; c++){
      p[r][c] = sp[(ty+1+r)*21 + (tx+1+c)];
      q[r][c] = st[(ty+1+r)*21 + (tx+1+c)];
    }
  float gxp = (p[0][2]+2.f*p[1][2]+p[2][2]) - (p[0][0]+2.f*p[1][0]+p[2][0]);
  float gyp = (p[2][0]+2.f*p[2][1]+p[2][2]) - (p[0][0]+2.f*p[0][1]+p[0][2]);
  float cvp = 4.f*p[1][1] - p[0][1] - p[1][0] - p[1][2] - p[2][1];
  float gxt = (q[0][2]+2.f*q[1][2]+q[2][2]) - (q[0][0]+2.f*q[1][0]+q[2][0]);
  float gyt = (q[2][0]+2.f*q[2][1]+q[2][2]) - (q[0][0]+2.f*q[0][1]+q[0][2]);
  float cvt = 4.f*q[1][1] - q[0][1] - q[1][0] - q[1][2] - q[2][1];

  float pmagc = pmg[(ty+1)*19 + tx+1];
  float tmagc = tmg[(ty+1)*19 + tx+1];
  float dirp = atan2f(gyp, gxp + 1e-8f);
  float dirt = atan2f(gyt, gxt + 1e-8f);
  float sd = fabsf(pmagc - tmagc);
  float dd = fabsf(dirp - dirt); dd = fminf(dd, TWO_PI_F - dd);
  float cd = fabsf(cvp - cvt);

  // boundary masks via incremental ring sums (mask entries are exact 0/1)
  const int cy = ty + 3, cx = tx + 3;
  float s1 = 0.f;
  #pragma unroll
  for (int dy = -1; dy <= 1; dy++)
    #pragma unroll
    for (int dx = -1; dx <= 1; dx++) s1 += smk[(cy+dy)*23 + cx+dx];
  float s2 = s1;
  #pragma unroll
  for (int d = -2; d <= 2; d++) s2 += smk[(cy-2)*23 + cx+d] + smk[(cy+2)*23 + cx+d];
  #pragma unroll
  for (int d = -1; d <= 1; d++) s2 += smk[(cy+d)*23 + cx-2] + smk[(cy+d)*23 + cx+2];
  float s3 = s2;
  #pragma unroll
  for (int d = -3; d <= 3; d++) s3 += smk[(cy-3)*23 + cx+d] + smk[(cy+3)*23 + cx+d];
  #pragma unroll
  for (int d = -2; d <= 2; d++) s3 += smk[(cy+d)*23 + cx-3] + smk[(cy+d)*23 + cx+3];

  float w1 = (s1 > 0.5f && s1 <  8.5f) ? 1.f : 0.f;
  float w2 = (s2 > 0.5f && s2 < 24.5f) ? 1.f : 0.f;
  float w3 = (s3 > 0.5f && s3 < 48.5f) ? 1.f : 0.f;

  // grad loss numerator: weights (1,2) for w1, (0.5,1) for w2/w3
  float gc = (sd + dd) * (w1 + 0.5f*(w2 + w3)) + cd * (2.f*w1 + w2 + w3);

  // smoothness: local std of pred over 3x3 box
  float s9 = 0.f, s9q = 0.f;
  #pragma unroll
  for (int r = 0; r < 3; r++)
    #pragma unroll
    for (int c = 0; c < 3; c++){ s9 += p[r][c]; s9q += p[r][c]*p[r][c]; }
  float lm = s9 * (1.f/9.f), lq = s9q * (1.f/9.f);
  float var = fmaxf(lq - lm*lm, 1e-8f);
  float smc = sqrtf(var) * w1;

  // slope continuity: Sobel of grad-magnitude fields
  float am[3][3], bm[3][3];
  #pragma unroll
  for (int r = 0; r < 3; r++)
    #pragma unroll
    for (int c = 0; c < 3; c++){
      am[r][c] = pmg[(ty+r)*19 + tx+c];
      bm[r][c] = tmg[(ty+r)*19 + tx+c];
    }
  float psx = (am[0][2]+2.f*am[1][2]+am[2][2]) - (am[0][0]+2.f*am[1][0]+am[2][0]);
  float psy = (am[2][0]+2.f*am[2][1]+am[2][2]) - (am[0][0]+2.f*am[0][1]+am[0][2]);
  float pch = sqrtf(psx*psx + psy*psy + 1e-8f);
  float tsx = (bm[0][2]+2.f*bm[1][2]+bm[2][2]) - (bm[0][0]+2.f*bm[1][0]+bm[2][0]);
  float tsy = (bm[2][0]+2.f*bm[2][1]+bm[2][2]) - (bm[0][0]+2.f*bm[0][1]+bm[0][2]);
  float tch = sqrtf(tsx*tsx + tsy*tsy + 1e-8f);
  float slc = fabsf(pch - tch) * w1;

  double g  = block_reduce_add((double)gc,  sc);
  double sm = block_reduce_add((double)smc, sc);
  double sl = block_reduce_add((double)slc, sc);
  if (tid == 0){
    // spread same-address atomic contention across NSLOT slots per sum
    int slot = (blockIdx.x + blockIdx.y * 7 + blockIdx.z * 13) & (NSLOT - 1);
    atomicAdd(&acc[0*NSLOT + slot], g);
    atomicAdd(&acc[1*NSLOT + slot], sm);
    atomicAdd(&acc[2*NSLOT + slot], sl);
  }
}

// ---------------------------------------------------------------------------
// FFT pass 1: per-row 1024-pt complex FFT of z = pred + i*target, in ws
// ---------------------------------------------------------------------------
__global__ __launch_bounds__(256)
void fft_rows_kernel(const float* __restrict__ pred, const float* __restrict__ targ,
                     float2* __restrict__ Z, int img0){
  __shared__ float2 buf[1024];
  __shared__ float2 tw[512];
  const int tid = threadIdx.x;
  const int row = blockIdx.x;
  const size_t ibase = ((size_t)(img0 + blockIdx.y) * HW + row) * HW;
  float2* zrow = Z + ((size_t)blockIdx.y * HW + row) * HW;

  for (int i = tid; i < 512; i += 256){
    float s, c; sincosf(-TWO_PI_F * (float)i * (1.f/1024.f), &s, &c);
    tw[i] = make_float2(c, s);
  }
  #pragma unroll
  for (int j = 0; j < 4; j++){
    int e = tid + (j << 8);
    int r = __brev(e) >> 22;          // bit-reversed load
    buf[r] = make_float2(pred[ibase + e], targ[ibase + e]);
  }
  __syncthreads();
  for (int s = 0; s < 10; s++){
    int half = 1 << s;
    #pragma unroll
    for (int j = 0; j < 2; j++){
      int b = tid + (j << 8);
      int grp = b >> s;
      int pos = b & (half - 1);
      int i0 = (grp << (s+1)) + pos, i1 = i0 + half;
      float2 w = tw[pos << (9 - s)];
      float2 u = buf[i0], v = buf[i1];
      float2 t = cmulf(w, v);
      buf[i0] = make_float2(u.x + t.x, u.y + t.y);
      buf[i1] = make_float2(u.x - t.x, u.y - t.y);
    }
    __syncthreads();
  }
  #pragma unroll
  for (int j = 0; j < 4; j++){
    int e = tid + (j << 8);
    zrow[e] = buf[e];
  }
}

// ---------------------------------------------------------------------------
// In-place square transpose via 32x32 tile pairs
// ---------------------------------------------------------------------------
__global__ __launch_bounds__(256)
void transpose_kernel(float2* __restrict__ Z){
  const int ti = blockIdx.y, tj = blockIdx.x;
  if (tj < ti) return;                       // uniform early-exit (no barriers yet)
  __shared__ float2 A[32*33];
  __shared__ float2 B[32*33];
  float2* base = Z + (size_t)blockIdx.z * HW * HW;
  const int tx = threadIdx.x & 31, ty = threadIdx.x >> 5;   // ty in [0,8)
  const bool off = (ti != tj);
  #pragma unroll
  for (int k = 0; k < 4; k++){
    int r = ty + (k << 3);
    A[r*33+tx] = base[(size_t)(ti*32+r)*HW + tj*32+tx];
    if (off) B[r*33+tx] = base[(size_t)(tj*32+r)*HW + ti*32+tx];
  }
  __syncthreads();
  #pragma unroll
  for (int k = 0; k < 4; k++){
    int r = ty + (k << 3);
    base[(size_t)(tj*32+r)*HW + ti*32+tx] = A[tx*33+r];
    if (off) base[(size_t)(ti*32+r)*HW + tj*32+tx] = B[tx*33+r];
  }
}

// ---------------------------------------------------------------------------
// FFT pass 2 + frequency reduce. After transpose, Zt(a,y) = rowFFT(y,a).
// FFT of Zt row a gives G(a,k) = F(k, a) (bins k2 = a, all k1).
// Partner row ap = (-a) mod 1024 supplies Z(-k) for the Hermitian unpack:
//   pf = (Z(k)+conj(Z(-k)))/2 ; tf = (Z(k)-conj(Z(-k)))/(2i)
// acc rows: 3 += hf*(|pf|-|tf|)^2 ; 4 += hf*wrap(ph_p-ph_t)^2
// ---------------------------------------------------------------------------
__device__ __forceinline__ void freq_contrib(float2 Zk, float2 Zm, int k1, int k2,
                                             double& ms, double& ps){
  int di = k1 - 512, dj = k2 - 512;
  if (di*di + dj*dj < 94372) return;         // dist > 307.2  <=>  r2 >= 94372
  float pr = 0.5f*(Zk.x + Zm.x);
  float pi = 0.5f*(Zk.y - Zm.y);
  float tr = 0.5f*(Zk.y + Zm.y);
  float ti = 0.5f*(Zm.x - Zk.x);
  float pmv = sqrtf(pr*pr + pi*pi);
  float tmv = sqrtf(tr*tr + ti*ti);
  float dm = pmv - tmv;
  ms += (double)(dm*dm);
  float re = pr*tr + pi*ti;                  // Re(pf * conj(tf))
  float im = pi*tr - pr*ti;                  // Im(pf * conj(tf))
  float pd = atan2f(im, re);                 // wrapped phase difference
  ps += (double)(pd*pd);
}

__global__ __launch_bounds__(256)
void fft_cols_reduce_kernel(const float2* __restrict__ Z, double* __restrict__ acc){
  __shared__ float2 b1[1024];
  __shared__ float2 b2[1024];
  __shared__ float2 tw[512];
  __shared__ double sc[4];
  const int tid = threadIdx.x;
  const int a  = blockIdx.x;                 // 0..512
  const int ap = (1024 - a) & 1023;
  const float2* base = Z + (size_t)blockIdx.y * HW * HW;

  for (int i = tid; i < 512; i += 256){
    float s, c; sincosf(-TWO_PI_F * (float)i * (1.f/1024.f), &s, &c);
    tw[i] = make_float2(c, s);
  }
  #pragma unroll
  for (int j = 0; j < 4; j++){
    int e = tid + (j << 8);
    int r = __brev(e) >> 22;
    b1[r] = base[(size_t)a  * HW + e];
    b2[r] = base[(size_t)ap * HW + e];
  }
  __syncthreads();
  for (int s = 0; s < 10; s++){
    int half = 1 << s;
    #pragma unroll
    for (int j = 0; j < 2; j++){
      int b = tid + (j << 8);
      int grp = b >> s;
      int pos = b & (half - 1);
      int i0 = (grp << (s+1)) + pos, i1 = i0 + half;
      float2 w = tw[pos << (9 - s)];
      float2 u = b1[i0], v = b1[i1];
      float2 t = cmulf(w, v);
      b1[i0] = make_float2(u.x + t.x, u.y + t.y);
      b1[i1] = make_float2(u.x - t.x, u.y - t.y);
      u = b2[i0]; v = b2[i1];
      t = cmulf(w, v);
      b2[i0] = make_float2(u.x + t.x, u.y + t.y);
      b2[i1] = make_float2(u.x - t.x, u.y - t.y);
    }
    __syncthreads();
  }

  double ms = 0.0, ps = 0.0;
  const bool two = (a != ap);                // self-paired rows 0 and 512
  #pragma unroll
  for (int j = 0; j < 4; j++){
    int k  = tid + (j << 8);
    int km = (1024 - k) & 1023;
    freq_contrib(b1[k], b2[km], k, a, ms, ps);
    if (two) freq_contrib(b2[k], b1[km], k, ap, ms, ps);
  }
  ms = block_reduce_add(ms, sc);
  ps = block_reduce_add(ps, sc);
  if (tid == 0){
    int slot = (blockIdx.x + blockIdx.y * 11) & (NSLOT - 1);
    atomicAdd(&acc[3*NSLOT + slot], ms);
    atomicAdd(&acc[4*NSLOT + slot], ps);
  }
}

// ---------------------------------------------------------------------------
// Single wave of 64 threads: lane t owns slot t of each sum; butterfly-reduce.
// ---------------------------------------------------------------------------
__global__ void finalize_kernel(const double* __restrict__ acc, float* __restrict__ out){
  const int t = threadIdx.x;   // 64 threads
  double v[5];
  #pragma unroll
  for (int s = 0; s < 5; s++) v[s] = acc[s*NSLOT + t];
  #pragma unroll
  for (int o = 32; o > 0; o >>= 1)
    #pragma unroll
    for (int s = 0; s < 5; s++) v[s] += __shfl_down(v[s], o, 64);
  if (t == 0){
    const double inv = 1.0 / 8388608.0;      // mean over 8*1024*1024
    double grad   = v[0] * inv / 3.0;        // / len(bms)
    double smooth = v[1] * inv;
    double slope  = v[2] * inv;
    double freq   = (v[3] + 2.0 * v[4]) * inv;
    double total  = 2.0*grad + 1.5*freq + 3.0*smooth + 2.0*slope;
    out[0] = (float)total;
    out[1] = (float)grad;
    out[2] = (float)freq;
    out[3] = (float)smooth;
    out[4] = (float)slope;
  }
}

extern "C" void kernel_launch(void* const* d_in, const int* in_sizes, int n_in,
                              void* d_out, int out_size, void* d_ws, size_t ws_size,
                              hipStream_t stream){
  const float* pred = (const float*)d_in[0];
  const float* targ = (const float*)d_in[1];
  const float* mask = (const float*)d_in[2];
  double* acc = (double*)d_ws;
  float2* Z = (float2*)((char*)d_ws + 4096);
  const size_t zimg = (size_t)HW * HW * sizeof(float2);   // 8 MiB per image

  int cmax = 1;
  if (ws_size > 4096){
    size_t c = (ws_size - 4096) / zimg;
    if (c > 8) c = 8;
    if (c < 1) c = 1;
    cmax = (int)c;
  }

  zero_acc_kernel<<<2, 256, 0, stream>>>(acc);
  spatial_kernel<<<dim3(64, 64, 8), 256, 0, stream>>>(pred, targ, mask, acc);
  for (int i0 = 0; i0 < 8; i0 += cmax){
    int c = (8 - i0 < cmax) ? (8 - i0) : cmax;
    fft_rows_kernel<<<dim3(1024, c), 256, 0, stream>>>(pred, targ, Z, i0);
    transpose_kernel<<<dim3(32, 32, c), 256, 0, stream>>>(Z);
    fft_cols_reduce_kernel<<<dim3(513, c), 256, 0, stream>>>(Z, acc);
  }
  finalize_kernel<<<1, 64, 0, stream>>>(acc, (float*)d_out);
}

// Round 3
// 338.844 us; speedup vs baseline: 4.3979x; 1.1634x over previous
//
#include <hip/hip_runtime.h>

#define HW 1024
#define TWO_PI_F 6.28318530717958647692f
#define NSLOT 64   // atomic spreading: 64 slots per accumulator, 5 accumulators

__device__ __forceinline__ float2 cmulf(float2 a, float2 b){
  return make_float2(a.x*b.x - a.y*b.y, a.x*b.y + a.y*b.x);
}

// 256-thread block reduction of a double (4 waves of 64)
__device__ __forceinline__ double block_reduce_add(double v, double* sc){
  int tid = threadIdx.x;
  #pragma unroll
  for (int o = 32; o > 0; o >>= 1) v += __shfl_down(v, o, 64);
  __syncthreads();                 // protect sc reuse across successive calls
  if ((tid & 63) == 0) sc[tid >> 6] = v;
  __syncthreads();
  return sc[0] + sc[1] + sc[2] + sc[3];
}

__global__ void zero_acc_kernel(double* acc){
  int i = threadIdx.x + blockIdx.x * blockDim.x;
  if (i < 5 * NSLOT) acc[i] = 0.0;
}

// ---------------------------------------------------------------------------
// Spatial half: grad/dir/curv losses (3 boundary widths), smoothness, slope
// continuity. One 16x16 output tile per block, halo 3. Accumulates 3 sums.
// acc rows: 0=grad numerator, 1=smooth, 2=slope (each NSLOT wide)
// ---------------------------------------------------------------------------
__global__ __launch_bounds__(256)
void spatial_kernel(const float* __restrict__ pred, const float* __restrict__ targ,
                    const float* __restrict__ mask, double* __restrict__ acc){
  __shared__ float sp[20*21];   // pred, halo 2, padded stride 21
  __shared__ float st[20*21];   // target
  __shared__ float smk[22*23];  // mask, halo 3, stride 23 (float staging only)
  __shared__ unsigned mrow[22]; // bit-packed mask rows (bit x = column x of tile)
  __shared__ float pmg[18*19];  // pred grad magnitude, halo 1, stride 19
  __shared__ float tmg[18*19];  // target grad magnitude
  __shared__ double sc[4];

  const int tid = threadIdx.x;
  const int x0 = blockIdx.x << 4, y0 = blockIdx.y << 4;
  const size_t ib = (size_t)blockIdx.z * ((size_t)HW * HW);

  // load pred/target with halo 2 (zero outside image)
  for (int i = tid; i < 400; i += 256){
    int a = i / 20, b = i % 20;
    int gy = y0 - 2 + a, gx = x0 - 2 + b;
    float pv = 0.f, tv = 0.f;
    if ((unsigned)gy < HW && (unsigned)gx < HW){
      size_t idx = ib + (size_t)gy * HW + gx;
      pv = pred[idx]; tv = targ[idx];
    }
    sp[a*21+b] = pv; st[a*21+b] = tv;
  }
  // load mask with halo 3 (coalesced float staging)
  for (int i = tid; i < 484; i += 256){
    int a = i / 22, b = i % 22;
    int gy = y0 - 3 + a, gx = x0 - 3 + b;
    float v = 0.f;
    if ((unsigned)gy < HW && (unsigned)gx < HW) v = mask[ib + (size_t)gy * HW + gx];
    smk[a*23+b] = v;
  }
  __syncthreads();

  // pack mask rows into bits (mask values are exact 0/1)
  if (tid < 22){
    unsigned w = 0u;
    #pragma unroll
    for (int x = 0; x < 22; x++)
      w |= (smk[tid*23 + x] > 0.5f) ? (1u << x) : 0u;
    mrow[tid] = w;
  }

  // gradient magnitude over halo-1 region (zero OUTSIDE image: conv zero-pads
  // p_mag itself, so OOB entries must be exactly 0, not sqrt(1e-8))
  for (int i = tid; i < 324; i += 256){
    int iy = i / 18, ix = i % 18;
    int gy = y0 - 1 + iy, gx = x0 - 1 + ix;
    float pv = 0.f, tv = 0.f;
    if ((unsigned)gy < HW && (unsigned)gx < HW){
      float a00=sp[(iy  )*21+ix], a01=sp[(iy  )*21+ix+1], a02=sp[(iy  )*21+ix+2];
      float a10=sp[(iy+1)*21+ix],                          a12=sp[(iy+1)*21+ix+2];
      float a20=sp[(iy+2)*21+ix], a21=sp[(iy+2)*21+ix+1], a22=sp[(iy+2)*21+ix+2];
      float gxp = (a02 + 2.f*a12 + a22) - (a00 + 2.f*a10 + a20);
      float gyp = (a20 + 2.f*a21 + a22) - (a00 + 2.f*a01 + a02);
      pv = sqrtf(gxp*gxp + gyp*gyp + 1e-8f);
      float b00=st[(iy  )*21+ix], b01=st[(iy  )*21+ix+1], b02=st[(iy  )*21+ix+2];
      float b10=st[(iy+1)*21+ix],                          b12=st[(iy+1)*21+ix+2];
      float b20=st[(iy+2)*21+ix], b21=st[(iy+2)*21+ix+1], b22=st[(iy+2)*21+ix+2];
      float gxt = (b02 + 2.f*b12 + b22) - (b00 + 2.f*b10 + b20);
      float gyt = (b20 + 2.f*b21 + b22) - (b00 + 2.f*b01 + b02);
      tv = sqrtf(gxt*gxt + gyt*gyt + 1e-8f);
    }
    pmg[iy*19+ix] = pv; tmg[iy*19+ix] = tv;
  }
  __syncthreads();

  // per-pixel losses (all 256 center pixels in-bounds: 1024 % 16 == 0)
  const int ty = tid >> 4, tx = tid & 15;

  float p[3][3], q[3][3];
  #pragma unroll
  for (int r = 0; r < 3; r++)
    #pragma unroll
    for (int c = 0; c < 3; c++){
      p[r][c] = sp[(ty+1+r)*21 + (tx+1+c)];
      q[r][c] = st[(ty+1+r)*21 + (tx+1+c)];
    }
  float gxp = (p[0][2]+2.f*p[1][2]+p[2][2]) - (p[0][0]+2.f*p[1][0]+p[2][0]);
  float gyp = (p[2][0]+2.f*p[2][1]+p[2][2]) - (p[0][0]+2.f*p[0][1]+p[0][2]);
  float cvp = 4.f*p[1][1] - p[0][1] - p[1][0] - p[1][2] - p[2][1];
  float gxt = (q[0][2]+2.f*q[1][2]+q[2][2]) - (q[0][0]+2.f*q[1][0]+q[2][0]);
  float gyt = (q[2][0]+2.f*q[2][1]+q[2][2]) - (q[0][0]+2.f*q[0][1]+q[0][2]);
  float cvt = 4.f*q[1][1] - q[0][1] - q[1][0] - q[1][2] - q[2][1];

  float pmagc = pmg[(ty+1)*19 + tx+1];
  float tmagc = tmg[(ty+1)*19 + tx+1];
  float sd = fabsf(pmagc - tmagc);
  // wrapped |dir_p - dir_t| via single atan2 of cross/dot:
  //   min(|a-b|, 2pi-|a-b|) == |atan2(sin(a-b), cos(a-b))|,
  //   sin(a-b) ~ cross, cos(a-b) ~ dot (positive scale r1*r2 cancels)
  float x1 = gxp + 1e-8f, y1 = gyp;
  float x2 = gxt + 1e-8f, y2 = gyt;
  float dd = fabsf(atan2f(y1*x2 - x1*y2, x1*x2 + y1*y2));
  float cd = fabsf(cvp - cvt);

  // boundary box sums via bit-packed rows + popcount (exact integer counts)
  // center column in tile = tx+3; s1 window cols tx+2..tx+4, s2 tx+1..tx+5,
  // s3 tx..tx+6; rows ty..ty+6 around center row ty+3.
  int s1 = 0, s2 = 0, s3 = 0;
  #pragma unroll
  for (int j = 0; j < 7; j++){
    unsigned w7 = (mrow[ty + j] >> tx) & 0x7Fu;
    s3 += __popc(w7);
    if (j >= 1 && j <= 5) s2 += __popc((w7 >> 1) & 0x1Fu);
    if (j >= 2 && j <= 4) s1 += __popc((w7 >> 2) & 0x7u);
  }
  float w1 = (s1 > 0 && s1 <  9) ? 1.f : 0.f;
  float w2 = (s2 > 0 && s2 < 25) ? 1.f : 0.f;
  float w3 = (s3 > 0 && s3 < 49) ? 1.f : 0.f;

  // grad loss numerator: weights (1,2) for w1, (0.5,1) for w2/w3
  float gc = (sd + dd) * (w1 + 0.5f*(w2 + w3)) + cd * (2.f*w1 + w2 + w3);

  // smoothness: local std of pred over 3x3 box
  float s9 = 0.f, s9q = 0.f;
  #pragma unroll
  for (int r = 0; r < 3; r++)
    #pragma unroll
    for (int c = 0; c < 3; c++){ s9 += p[r][c]; s9q += p[r][c]*p[r][c]; }
  float lm = s9 * (1.f/9.f), lq = s9q * (1.f/9.f);
  float var = fmaxf(lq - lm*lm, 1e-8f);
  float smc = sqrtf(var) * w1;

  // slope continuity: Sobel of grad-magnitude fields
  float am[3][3], bm[3][3];
  #pragma unroll
  for (int r = 0; r < 3; r++)
    #pragma unroll
    for (int c = 0; c < 3; c++){
      am[r][c] = pmg[(ty+r)*19 + tx+c];
      bm[r][c] = tmg[(ty+r)*19 + tx+c];
    }
  float psx = (am[0][2]+2.f*am[1][2]+am[2][2]) - (am[0][0]+2.f*am[1][0]+am[2][0]);
  float psy = (am[2][0]+2.f*am[2][1]+am[2][2]) - (am[0][0]+2.f*am[0][1]+am[0][2]);
  float pch = sqrtf(psx*psx + psy*psy + 1e-8f);
  float tsx = (bm[0][2]+2.f*bm[1][2]+bm[2][2]) - (bm[0][0]+2.f*bm[1][0]+bm[2][0]);
  float tsy = (bm[2][0]+2.f*bm[2][1]+bm[2][2]) - (bm[0][0]+2.f*bm[0][1]+bm[0][2]);
  float tch = sqrtf(tsx*tsx + tsy*tsy + 1e-8f);
  float slc = fabsf(pch - tch) * w1;

  double g  = block_reduce_add((double)gc,  sc);
  double sm = block_reduce_add((double)smc, sc);
  double sl = block_reduce_add((double)slc, sc);
  if (tid == 0){
    // spread same-address atomic contention across NSLOT slots per sum
    int slot = (blockIdx.x + blockIdx.y * 7 + blockIdx.z * 13) & (NSLOT - 1);
    atomicAdd(&acc[0*NSLOT + slot], g);
    atomicAdd(&acc[1*NSLOT + slot], sm);
    atomicAdd(&acc[2*NSLOT + slot], sl);
  }
}

// ---------------------------------------------------------------------------
// Radix-4 double-stage butterfly (two merged radix-2 DIT layers):
// quad {i, i+h, i+2h, i+3h}; stage-s twiddle w1, stage-(s+1) twiddles
// (w2, -i*w2). Derived from verified radix-2 indexing.
// ---------------------------------------------------------------------------
__device__ __forceinline__ void quad_butterfly(float2* buf, int i, int h,
                                               float2 w1, float2 w2){
  float2 a0 = buf[i], a1 = buf[i+h], a2 = buf[i+2*h], a3 = buf[i+3*h];
  float2 t  = cmulf(w1, a1);
  float2 b0 = make_float2(a0.x + t.x, a0.y + t.y);
  float2 b1 = make_float2(a0.x - t.x, a0.y - t.y);
  float2 u  = cmulf(w1, a3);
  float2 b2 = make_float2(a2.x + u.x, a2.y + u.y);
  float2 b3 = make_float2(a2.x - u.x, a2.y - u.y);
  float2 v  = cmulf(w2, b2);
  float2 z  = cmulf(w2, b3);
  float2 zz = make_float2(z.y, -z.x);        // (-i) * z
  buf[i]     = make_float2(b0.x + v.x,  b0.y + v.y);
  buf[i+2*h] = make_float2(b0.x - v.x,  b0.y - v.y);
  buf[i+h]   = make_float2(b1.x + zz.x, b1.y + zz.y);
  buf[i+3*h] = make_float2(b1.x - zz.x, b1.y - zz.y);
}

// ---------------------------------------------------------------------------
// FFT pass 1: per-row 1024-pt complex FFT of z = pred + i*target, in ws
// ---------------------------------------------------------------------------
__global__ __launch_bounds__(256)
void fft_rows_kernel(const float* __restrict__ pred, const float* __restrict__ targ,
                     float2* __restrict__ Z, int img0){
  __shared__ float2 buf[1024];
  __shared__ float2 tw[512];
  const int tid = threadIdx.x;
  const int row = blockIdx.x;
  const size_t ibase = ((size_t)(img0 + blockIdx.y) * HW + row) * HW;
  float2* zrow = Z + ((size_t)blockIdx.y * HW + row) * HW;

  for (int i = tid; i < 512; i += 256){
    float s, c; sincosf(-TWO_PI_F * (float)i * (1.f/1024.f), &s, &c);
    tw[i] = make_float2(c, s);
  }
  #pragma unroll
  for (int j = 0; j < 4; j++){
    int e = tid + (j << 8);
    int r = __brev(e) >> 22;          // bit-reversed load
    buf[r] = make_float2(pred[ibase + e], targ[ibase + e]);
  }
  __syncthreads();
  #pragma unroll
  for (int s = 0; s < 10; s += 2){
    int h = 1 << s;
    int grp = tid >> s;
    int pos = tid & (h - 1);
    int i = (grp << (s + 2)) + pos;
    float2 w1 = tw[pos << (9 - s)];
    float2 w2 = tw[pos << (8 - s)];
    quad_butterfly(buf, i, h, w1, w2);
    __syncthreads();
  }
  #pragma unroll
  for (int j = 0; j < 4; j++){
    int e = tid + (j << 8);
    zrow[e] = buf[e];
  }
}

// ---------------------------------------------------------------------------
// In-place square transpose via 32x32 tile pairs
// ---------------------------------------------------------------------------
__global__ __launch_bounds__(256)
void transpose_kernel(float2* __restrict__ Z){
  const int ti = blockIdx.y, tj = blockIdx.x;
  if (tj < ti) return;                       // uniform early-exit (no barriers yet)
  __shared__ float2 A[32*33];
  __shared__ float2 B[32*33];
  float2* base = Z + (size_t)blockIdx.z * HW * HW;
  const int tx = threadIdx.x & 31, ty = threadIdx.x >> 5;   // ty in [0,8)
  const bool off = (ti != tj);
  #pragma unroll
  for (int k = 0; k < 4; k++){
    int r = ty + (k << 3);
    A[r*33+tx] = base[(size_t)(ti*32+r)*HW + tj*32+tx];
    if (off) B[r*33+tx] = base[(size_t)(tj*32+r)*HW + ti*32+tx];
  }
  __syncthreads();
  #pragma unroll
  for (int k = 0; k < 4; k++){
    int r = ty + (k << 3);
    base[(size_t)(tj*32+r)*HW + ti*32+tx] = A[tx*33+r];
    if (off) base[(size_t)(ti*32+r)*HW + tj*32+tx] = B[tx*33+r];
  }
}

// ---------------------------------------------------------------------------
// FFT pass 2 + frequency reduce. After transpose, Zt(a,y) = rowFFT(y,a).
// FFT of Zt row a gives G(a,k) = F(k, a) (bins k2 = a, all k1).
// Partner row ap = (-a) mod 1024 supplies Z(-k) for the Hermitian unpack:
//   pf = (Z(k)+conj(Z(-k)))/2 ; tf = (Z(k)-conj(Z(-k)))/(2i)
// acc rows: 3 += hf*(|pf|-|tf|)^2 ; 4 += hf*wrap(ph_p-ph_t)^2
// ---------------------------------------------------------------------------
__device__ __forceinline__ void freq_contrib(float2 Zk, float2 Zm, int k1, int k2,
                                             double& ms, double& ps){
  int di = k1 - 512, dj = k2 - 512;
  if (di*di + dj*dj < 94372) return;         // dist > 307.2  <=>  r2 >= 94372
  float pr = 0.5f*(Zk.x + Zm.x);
  float pi = 0.5f*(Zk.y - Zm.y);
  float tr = 0.5f*(Zk.y + Zm.y);
  float ti = 0.5f*(Zm.x - Zk.x);
  float pmv = sqrtf(pr*pr + pi*pi);
  float tmv = sqrtf(tr*tr + ti*ti);
  float dm = pmv - tmv;
  ms += (double)(dm*dm);
  float re = pr*tr + pi*ti;                  // Re(pf * conj(tf))
  float im = pi*tr - pr*ti;                  // Im(pf * conj(tf))
  float pd = atan2f(im, re);                 // wrapped phase difference
  ps += (double)(pd*pd);
}

__global__ __launch_bounds__(256)
void fft_cols_reduce_kernel(const float2* __restrict__ Z, double* __restrict__ acc){
  __shared__ float2 b1[1024];
  __shared__ float2 b2[1024];
  __shared__ float2 tw[512];
  __shared__ double sc[4];
  const int tid = threadIdx.x;
  const int a  = blockIdx.x;                 // 0..512
  const int ap = (1024 - a) & 1023;
  const float2* base = Z + (size_t)blockIdx.y * HW * HW;

  for (int i = tid; i < 512; i += 256){
    float s, c; sincosf(-TWO_PI_F * (float)i * (1.f/1024.f), &s, &c);
    tw[i] = make_float2(c, s);
  }
  #pragma unroll
  for (int j = 0; j < 4; j++){
    int e = tid + (j << 8);
    int r = __brev(e) >> 22;
    b1[r] = base[(size_t)a  * HW + e];
    b2[r] = base[(size_t)ap * HW + e];
  }
  __syncthreads();
  #pragma unroll
  for (int s = 0; s < 10; s += 2){
    int h = 1 << s;
    int grp = tid >> s;
    int pos = tid & (h - 1);
    int i = (grp << (s + 2)) + pos;
    float2 w1 = tw[pos << (9 - s)];
    float2 w2 = tw[pos << (8 - s)];
    quad_butterfly(b1, i, h, w1, w2);
    quad_butterfly(b2, i, h, w1, w2);
    __syncthreads();
  }

  double ms = 0.0, ps = 0.0;
  const bool two = (a != ap);                // self-paired rows 0 and 512
  #pragma unroll
  for (int j = 0; j < 4; j++){
    int k  = tid + (j << 8);
    int km = (1024 - k) & 1023;
    freq_contrib(b1[k], b2[km], k, a, ms, ps);
    if (two) freq_contrib(b2[k], b1[km], k, ap, ms, ps);
  }
  ms = block_reduce_add(ms, sc);
  ps = block_reduce_add(ps, sc);
  if (tid == 0){
    int slot = (blockIdx.x + blockIdx.y * 11) & (NSLOT - 1);
    atomicAdd(&acc[3*NSLOT + slot], ms);
    atomicAdd(&acc[4*NSLOT + slot], ps);
  }
}

// ---------------------------------------------------------------------------
// Single wave of 64 threads: lane t owns slot t of each sum; butterfly-reduce.
// ---------------------------------------------------------------------------
__global__ void finalize_kernel(const double* __restrict__ acc, float* __restrict__ out){
  const int t = threadIdx.x;   // 64 threads
  double v[5];
  #pragma unroll
  for (int s = 0; s < 5; s++) v[s] = acc[s*NSLOT + t];
  #pragma unroll
  for (int o = 32; o > 0; o >>= 1)
    #pragma unroll
    for (int s = 0; s < 5; s++) v[s] += __shfl_down(v[s], o, 64);
  if (t == 0){
    const double inv = 1.0 / 8388608.0;      // mean over 8*1024*1024
    double grad   = v[0] * inv / 3.0;        // / len(bms)
    double smooth = v[1] * inv;
    double slope  = v[2] * inv;
    double freq   = (v[3] + 2.0 * v[4]) * inv;
    double total  = 2.0*grad + 1.5*freq + 3.0*smooth + 2.0*slope;
    out[0] = (float)total;
    out[1] = (float)grad;
    out[2] = (float)freq;
    out[3] = (float)smooth;
    out[4] = (float)slope;
  }
}

extern "C" void kernel_launch(void* const* d_in, const int* in_sizes, int n_in,
                              void* d_out, int out_size, void* d_ws, size_t ws_size,
                              hipStream_t stream){
  const float* pred = (const float*)d_in[0];
  const float* targ = (const float*)d_in[1];
  const float* mask = (const float*)d_in[2];
  double* acc = (double*)d_ws;
  float2* Z = (float2*)((char*)d_ws + 4096);
  const size_t zimg = (size_t)HW * HW * sizeof(float2);   // 8 MiB per image

  int cmax = 1;
  if (ws_size > 4096){
    size_t c = (ws_size - 4096) / zimg;
    if (c > 8) c = 8;
    if (c < 1) c = 1;
    cmax = (int)c;
  }

  zero_acc_kernel<<<2, 256, 0, stream>>>(acc);
  spatial_kernel<<<dim3(64, 64, 8), 256, 0, stream>>>(pred, targ, mask, acc);
  for (int i0 = 0; i0 < 8; i0 += cmax){
    int c = (8 - i0 < cmax) ? (8 - i0) : cmax;
    fft_rows_kernel<<<dim3(1024, c), 256, 0, stream>>>(pred, targ, Z, i0);
    transpose_kernel<<<dim3(32, 32, c), 256, 0, stream>>>(Z);
    fft_cols_reduce_kernel<<<dim3(513, c), 256, 0, stream>>>(Z, acc);
  }
  finalize_kernel<<<1, 64, 0, stream>>>(acc, (float*)d_out);
}

// Round 4
// 304.669 us; speedup vs baseline: 4.8913x; 1.1122x over previous
//
#include <hip/hip_runtime.h>

#define HW 1024
#define TWO_PI_F 6.28318530717958647692f
#define NSLOT 64   // atomic spreading: 64 slots per accumulator, 5 accumulators

__device__ __forceinline__ float2 cmulf(float2 a, float2 b){
  return make_float2(a.x*b.x - a.y*b.y, a.x*b.y + a.y*b.x);
}

// fast atan2: octant reduction + 9th-order odd minimax poly, max err ~1e-4 rad.
// Replaces ~90-instr libm atan2f with ~18 VALU ops. (0,0) -> 0 via rcp clamp.
__device__ __forceinline__ float fast_atan2f(float y, float x){
  float ax = fabsf(x), ay = fabsf(y);
  float mx = fmaxf(ax, ay), mn = fminf(ax, ay);
  float a  = mn * __builtin_amdgcn_rcpf(fmaxf(mx, 1e-37f));
  float s  = a * a;
  float r  = ((((0.0208351f*s - 0.085133f)*s + 0.180141f)*s - 0.3302995f)*s
              + 0.999866f) * a;
  r = (ay > ax) ? 1.57079632679f - r : r;
  r = (x < 0.f) ? 3.14159265359f - r : r;
  return (y < 0.f) ? -r : r;
}

// 256-thread block reduction (4 waves of 64), float version
__device__ __forceinline__ float block_reduce_add_f(float v, float* sc){
  int tid = threadIdx.x;
  #pragma unroll
  for (int o = 32; o > 0; o >>= 1) v += __shfl_down(v, o, 64);
  __syncthreads();
  if ((tid & 63) == 0) sc[tid >> 6] = v;
  __syncthreads();
  return sc[0] + sc[1] + sc[2] + sc[3];
}

// double version (used by fft_cols reduce; only 4104 blocks, cost negligible)
__device__ __forceinline__ double block_reduce_add(double v, double* sc){
  int tid = threadIdx.x;
  #pragma unroll
  for (int o = 32; o > 0; o >>= 1) v += __shfl_down(v, o, 64);
  __syncthreads();
  if ((tid & 63) == 0) sc[tid >> 6] = v;
  __syncthreads();
  return sc[0] + sc[1] + sc[2] + sc[3];
}

__global__ void zero_acc_kernel(double* acc){
  int i = threadIdx.x + blockIdx.x * blockDim.x;
  if (i < 5 * NSLOT) acc[i] = 0.0;
}

// ---------------------------------------------------------------------------
// Spatial half: 32x32 output tile per block, 4 vertically-consecutive pixels
// per thread (ty in [0,8), tx in [0,32)). Rolling 3x3 register windows for
// sp/st (Sobel+curv+smooth) and pmg/tmg (slope); bit-packed mask rows with
// per-row popcounts shared across the 4 pixel windows.
// acc rows: 0=grad numerator, 1=smooth, 2=slope (each NSLOT wide)
// ---------------------------------------------------------------------------
__global__ __launch_bounds__(256)
void spatial_kernel(const float* __restrict__ pred, const float* __restrict__ targ,
                    const float* __restrict__ mask, double* __restrict__ acc){
  __shared__ float sp[36*37];    // pred, halo 2, padded stride 37
  __shared__ float st[36*37];    // target
  __shared__ float smkf[38*39];  // mask float staging, halo 3, stride 39
  __shared__ unsigned long long mrow[38]; // bit-packed mask rows (bit x = tile col x)
  __shared__ float pmg[34*35];   // pred grad magnitude, halo 1, stride 35
  __shared__ float tmg[34*35];   // target grad magnitude
  __shared__ float sc[4];

  const int tid = threadIdx.x;
  const int x0 = blockIdx.x << 5, y0 = blockIdx.y << 5;
  const size_t ib = (size_t)blockIdx.z * ((size_t)HW * HW);

  // load pred/target with halo 2 (zero outside image)
  for (int i = tid; i < 1296; i += 256){
    int a = i / 36, b = i % 36;
    int gy = y0 - 2 + a, gx = x0 - 2 + b;
    float pv = 0.f, tv = 0.f;
    if ((unsigned)gy < HW && (unsigned)gx < HW){
      size_t idx = ib + (size_t)gy * HW + gx;
      pv = pred[idx]; tv = targ[idx];
    }
    sp[a*37+b] = pv; st[a*37+b] = tv;
  }
  // load mask with halo 3 (coalesced float staging)
  for (int i = tid; i < 1444; i += 256){
    int a = i / 38, b = i % 38;
    int gy = y0 - 3 + a, gx = x0 - 3 + b;
    float v = 0.f;
    if ((unsigned)gy < HW && (unsigned)gx < HW) v = mask[ib + (size_t)gy * HW + gx];
    smkf[a*39+b] = v;
  }
  __syncthreads();

  // pack mask rows into bits (mask values are exact 0/1)
  if (tid < 38){
    unsigned long long w = 0ull;
    #pragma unroll
    for (int x = 0; x < 38; x++)
      w |= (smkf[tid*39 + x] > 0.5f) ? (1ull << x) : 0ull;
    mrow[tid] = w;
  }

  // gradient-magnitude prepass over halo-1 region (34x34). OOB entries must be
  // exactly 0 (conv zero-pads p_mag itself), not sqrt(1e-8).
  for (int i = tid; i < 1156; i += 256){
    int iy = i / 34, ix = i % 34;
    int gy = y0 - 1 + iy, gx = x0 - 1 + ix;
    float pv = 0.f, tv = 0.f;
    if ((unsigned)gy < HW && (unsigned)gx < HW){
      int o = (iy)*37 + ix;   // sp row iy..iy+2 == image rows gy-1..gy+1
      float a00=sp[o], a01=sp[o+1], a02=sp[o+2];
      float a10=sp[o+37],           a12=sp[o+39];
      float a20=sp[o+74], a21=sp[o+75], a22=sp[o+76];
      float gxp = (a02 + 2.f*a12 + a22) - (a00 + 2.f*a10 + a20);
      float gyp = (a20 + 2.f*a21 + a22) - (a00 + 2.f*a01 + a02);
      pv = sqrtf(gxp*gxp + gyp*gyp + 1e-8f);
      float b00=st[o], b01=st[o+1], b02=st[o+2];
      float b10=st[o+37],           b12=st[o+39];
      float b20=st[o+74], b21=st[o+75], b22=st[o+76];
      float gxt = (b02 + 2.f*b12 + b22) - (b00 + 2.f*b10 + b20);
      float gyt = (b20 + 2.f*b21 + b22) - (b00 + 2.f*b01 + b02);
      tv = sqrtf(gxt*gxt + gyt*gyt + 1e-8f);
    }
    pmg[iy*35+ix] = pv; tmg[iy*35+ix] = tv;
  }
  __syncthreads();

  const int ty = tid >> 5, tx = tid & 31;
  const int r0 = ty << 2;            // first of 4 pixel rows for this thread

  // per-row mask popcounts for the 10 mask rows covering the 4 pixel windows
  // (pixel row r uses mask rows r..r+6; bits tx..tx+6 after >>tx)
  int c1[10], c2[10], c3[10];
  #pragma unroll
  for (int j = 0; j < 10; j++){
    unsigned w = (unsigned)(mrow[r0 + j] >> tx);
    c3[j] = __popc(w & 0x7Fu);
    c2[j] = __popc((w >> 1) & 0x1Fu);
    c1[j] = __popc((w >> 2) & 0x7u);
  }

  // rolling 3x3 windows: P/Q over sp/st (rows r+1..r+3), A/B over pmg/tmg (r..r+2)
  float P[3][3], Q[3][3], A[3][3], B[3][3];
  #pragma unroll
  for (int rr = 0; rr < 3; rr++)
    #pragma unroll
    for (int cc = 0; cc < 3; cc++){
      P[rr][cc] = sp[(r0+1+rr)*37 + tx+1+cc];
      Q[rr][cc] = st[(r0+1+rr)*37 + tx+1+cc];
      A[rr][cc] = pmg[(r0+rr)*35 + tx+cc];
      B[rr][cc] = tmg[(r0+rr)*35 + tx+cc];
    }

  float accg = 0.f, accs = 0.f, accl = 0.f;
  #pragma unroll
  for (int k = 0; k < 4; k++){
    if (k){
      #pragma unroll
      for (int cc = 0; cc < 3; cc++){
        P[0][cc]=P[1][cc]; P[1][cc]=P[2][cc]; P[2][cc]=sp[(r0+k+3)*37 + tx+1+cc];
        Q[0][cc]=Q[1][cc]; Q[1][cc]=Q[2][cc]; Q[2][cc]=st[(r0+k+3)*37 + tx+1+cc];
        A[0][cc]=A[1][cc]; A[1][cc]=A[2][cc]; A[2][cc]=pmg[(r0+k+2)*35 + tx+cc];
        B[0][cc]=B[1][cc]; B[1][cc]=B[2][cc]; B[2][cc]=tmg[(r0+k+2)*35 + tx+cc];
      }
    }
    float gxp = (P[0][2]+2.f*P[1][2]+P[2][2]) - (P[0][0]+2.f*P[1][0]+P[2][0]);
    float gyp = (P[2][0]+2.f*P[2][1]+P[2][2]) - (P[0][0]+2.f*P[0][1]+P[0][2]);
    float cvp = 4.f*P[1][1] - P[0][1] - P[1][0] - P[1][2] - P[2][1];
    float gxt = (Q[0][2]+2.f*Q[1][2]+Q[2][2]) - (Q[0][0]+2.f*Q[1][0]+Q[2][0]);
    float gyt = (Q[2][0]+2.f*Q[2][1]+Q[2][2]) - (Q[0][0]+2.f*Q[0][1]+Q[0][2]);
    float cvt = 4.f*Q[1][1] - Q[0][1] - Q[1][0] - Q[1][2] - Q[2][1];

    float sd = fabsf(A[1][1] - B[1][1]);
    // wrapped |dir_p - dir_t| = |atan2(cross, dot)| (positive scale cancels)
    float x1 = gxp + 1e-8f, y1 = gyp;
    float x2 = gxt + 1e-8f, y2 = gyt;
    float dd = fabsf(fast_atan2f(y1*x2 - x1*y2, x1*x2 + y1*y2));
    float cd = fabsf(cvp - cvt);

    int s1 = c1[k+2]+c1[k+3]+c1[k+4];
    int s2 = c2[k+1]+c2[k+2]+c2[k+3]+c2[k+4]+c2[k+5];
    int s3 = c3[k]+c3[k+1]+c3[k+2]+c3[k+3]+c3[k+4]+c3[k+5]+c3[k+6];
    float w1 = (s1 > 0 && s1 <  9) ? 1.f : 0.f;
    float w2 = (s2 > 0 && s2 < 25) ? 1.f : 0.f;
    float w3 = (s3 > 0 && s3 < 49) ? 1.f : 0.f;

    accg += (sd + dd) * (w1 + 0.5f*(w2 + w3)) + cd * (2.f*w1 + w2 + w3);

    // smoothness: local std of pred over 3x3 box
    float s9 = 0.f, s9q = 0.f;
    #pragma unroll
    for (int rr = 0; rr < 3; rr++)
      #pragma unroll
      for (int cc = 0; cc < 3; cc++){ s9 += P[rr][cc]; s9q += P[rr][cc]*P[rr][cc]; }
    float lm = s9 * (1.f/9.f), lq = s9q * (1.f/9.f);
    accs += sqrtf(fmaxf(lq - lm*lm, 1e-8f)) * w1;

    // slope continuity: Sobel of grad-magnitude fields
    float psx = (A[0][2]+2.f*A[1][2]+A[2][2]) - (A[0][0]+2.f*A[1][0]+A[2][0]);
    float psy = (A[2][0]+2.f*A[2][1]+A[2][2]) - (A[0][0]+2.f*A[0][1]+A[0][2]);
    float pch = sqrtf(psx*psx + psy*psy + 1e-8f);
    float tsx = (B[0][2]+2.f*B[1][2]+B[2][2]) - (B[0][0]+2.f*B[1][0]+B[2][0]);
    float tsy = (B[2][0]+2.f*B[2][1]+B[2][2]) - (B[0][0]+2.f*B[0][1]+B[0][2]);
    float tch = sqrtf(tsx*tsx + tsy*tsy + 1e-8f);
    accl += fabsf(pch - tch) * w1;
  }

  float g  = block_reduce_add_f(accg, sc);
  float sm = block_reduce_add_f(accs, sc);
  float sl = block_reduce_add_f(accl, sc);
  if (tid == 0){
    int slot = (blockIdx.x + blockIdx.y * 7 + blockIdx.z * 13) & (NSLOT - 1);
    atomicAdd(&acc[0*NSLOT + slot], (double)g);
    atomicAdd(&acc[1*NSLOT + slot], (double)sm);
    atomicAdd(&acc[2*NSLOT + slot], (double)sl);
  }
}

// ---------------------------------------------------------------------------
// Radix-4 double-stage butterfly (two merged radix-2 DIT layers):
// quad {i, i+h, i+2h, i+3h}; stage-s twiddle w1, stage-(s+1) twiddles
// (w2, -i*w2).
// ---------------------------------------------------------------------------
__device__ __forceinline__ void quad_butterfly(float2* buf, int i, int h,
                                               float2 w1, float2 w2){
  float2 a0 = buf[i], a1 = buf[i+h], a2 = buf[i+2*h], a3 = buf[i+3*h];
  float2 t  = cmulf(w1, a1);
  float2 b0 = make_float2(a0.x + t.x, a0.y + t.y);
  float2 b1 = make_float2(a0.x - t.x, a0.y - t.y);
  float2 u  = cmulf(w1, a3);
  float2 b2 = make_float2(a2.x + u.x, a2.y + u.y);
  float2 b3 = make_float2(a2.x - u.x, a2.y - u.y);
  float2 v  = cmulf(w2, b2);
  float2 z  = cmulf(w2, b3);
  float2 zz = make_float2(z.y, -z.x);        // (-i) * z
  buf[i]     = make_float2(b0.x + v.x,  b0.y + v.y);
  buf[i+2*h] = make_float2(b0.x - v.x,  b0.y - v.y);
  buf[i+h]   = make_float2(b1.x + zz.x, b1.y + zz.y);
  buf[i+3*h] = make_float2(b1.x - zz.x, b1.y - zz.y);
}

// ---------------------------------------------------------------------------
// FFT pass 1: per-row 1024-pt complex FFT of z = pred + i*target, in ws
// ---------------------------------------------------------------------------
__global__ __launch_bounds__(256)
void fft_rows_kernel(const float* __restrict__ pred, const float* __restrict__ targ,
                     float2* __restrict__ Z, int img0){
  __shared__ float2 buf[1024];
  __shared__ float2 tw[512];
  const int tid = threadIdx.x;
  const int row = blockIdx.x;
  const size_t ibase = ((size_t)(img0 + blockIdx.y) * HW + row) * HW;
  float2* zrow = Z + ((size_t)blockIdx.y * HW + row) * HW;

  for (int i = tid; i < 512; i += 256){
    float s, c; sincosf(-TWO_PI_F * (float)i * (1.f/1024.f), &s, &c);
    tw[i] = make_float2(c, s);
  }
  #pragma unroll
  for (int j = 0; j < 4; j++){
    int e = tid + (j << 8);
    int r = __brev(e) >> 22;          // bit-reversed load
    buf[r] = make_float2(pred[ibase + e], targ[ibase + e]);
  }
  __syncthreads();
  #pragma unroll
  for (int s = 0; s < 10; s += 2){
    int h = 1 << s;
    int grp = tid >> s;
    int pos = tid & (h - 1);
    int i = (grp << (s + 2)) + pos;
    float2 w1 = tw[pos << (9 - s)];
    float2 w2 = tw[pos << (8 - s)];
    quad_butterfly(buf, i, h, w1, w2);
    __syncthreads();
  }
  #pragma unroll
  for (int j = 0; j < 4; j++){
    int e = tid + (j << 8);
    zrow[e] = buf[e];
  }
}

// ---------------------------------------------------------------------------
// In-place square transpose via 32x32 tile pairs
// ---------------------------------------------------------------------------
__global__ __launch_bounds__(256)
void transpose_kernel(float2* __restrict__ Z){
  const int ti = blockIdx.y, tj = blockIdx.x;
  if (tj < ti) return;                       // uniform early-exit (no barriers yet)
  __shared__ float2 A[32*33];
  __shared__ float2 B[32*33];
  float2* base = Z + (size_t)blockIdx.z * HW * HW;
  const int tx = threadIdx.x & 31, ty = threadIdx.x >> 5;   // ty in [0,8)
  const bool off = (ti != tj);
  #pragma unroll
  for (int k = 0; k < 4; k++){
    int r = ty + (k << 3);
    A[r*33+tx] = base[(size_t)(ti*32+r)*HW + tj*32+tx];
    if (off) B[r*33+tx] = base[(size_t)(tj*32+r)*HW + ti*32+tx];
  }
  __syncthreads();
  #pragma unroll
  for (int k = 0; k < 4; k++){
    int r = ty + (k << 3);
    base[(size_t)(tj*32+r)*HW + ti*32+tx] = A[tx*33+r];
    if (off) base[(size_t)(ti*32+r)*HW + tj*32+tx] = B[tx*33+r];
  }
}

// ---------------------------------------------------------------------------
// FFT pass 2 + frequency reduce. Partner row ap = (-a) mod 1024 supplies
// Z(-k) for the Hermitian unpack:
//   pf = (Z(k)+conj(Z(-k)))/2 ; tf = (Z(k)-conj(Z(-k)))/(2i)
// acc rows: 3 += hf*(|pf|-|tf|)^2 ; 4 += hf*wrap(ph_p-ph_t)^2
// ---------------------------------------------------------------------------
__device__ __forceinline__ void freq_contrib(float2 Zk, float2 Zm, int k1, int k2,
                                             double& ms, double& ps){
  int di = k1 - 512, dj = k2 - 512;
  if (di*di + dj*dj < 94372) return;         // dist > 307.2  <=>  r2 >= 94372
  float pr = 0.5f*(Zk.x + Zm.x);
  float pi = 0.5f*(Zk.y - Zm.y);
  float tr = 0.5f*(Zk.y + Zm.y);
  float ti = 0.5f*(Zm.x - Zk.x);
  float pmv = sqrtf(pr*pr + pi*pi);
  float tmv = sqrtf(tr*tr + ti*ti);
  float dm = pmv - tmv;
  ms += (double)(dm*dm);
  float re = pr*tr + pi*ti;                  // Re(pf * conj(tf))
  float im = pi*tr - pr*ti;                  // Im(pf * conj(tf))
  float pd = fast_atan2f(im, re);            // wrapped phase difference
  ps += (double)(pd*pd);
}

__global__ __launch_bounds__(256)
void fft_cols_reduce_kernel(const float2* __restrict__ Z, double* __restrict__ acc){
  __shared__ float2 b1[1024];
  __shared__ float2 b2[1024];
  __shared__ float2 tw[512];
  __shared__ double sc[4];
  const int tid = threadIdx.x;
  const int a  = blockIdx.x;                 // 0..512
  const int ap = (1024 - a) & 1023;
  const float2* base = Z + (size_t)blockIdx.y * HW * HW;

  for (int i = tid; i < 512; i += 256){
    float s, c; sincosf(-TWO_PI_F * (float)i * (1.f/1024.f), &s, &c);
    tw[i] = make_float2(c, s);
  }
  #pragma unroll
  for (int j = 0; j < 4; j++){
    int e = tid + (j << 8);
    int r = __brev(e) >> 22;
    b1[r] = base[(size_t)a  * HW + e];
    b2[r] = base[(size_t)ap * HW + e];
  }
  __syncthreads();
  #pragma unroll
  for (int s = 0; s < 10; s += 2){
    int h = 1 << s;
    int grp = tid >> s;
    int pos = tid & (h - 1);
    int i = (grp << (s + 2)) + pos;
    float2 w1 = tw[pos << (9 - s)];
    float2 w2 = tw[pos << (8 - s)];
    quad_butterfly(b1, i, h, w1, w2);
    quad_butterfly(b2, i, h, w1, w2);
    __syncthreads();
  }

  double ms = 0.0, ps = 0.0;
  const bool two = (a != ap);                // self-paired rows 0 and 512
  #pragma unroll
  for (int j = 0; j < 4; j++){
    int k  = tid + (j << 8);
    int km = (1024 - k) & 1023;
    freq_contrib(b1[k], b2[km], k, a, ms, ps);
    if (two) freq_contrib(b2[k], b1[km], k, ap, ms, ps);
  }
  ms = block_reduce_add(ms, sc);
  ps = block_reduce_add(ps, sc);
  if (tid == 0){
    int slot = (blockIdx.x + blockIdx.y * 11) & (NSLOT - 1);
    atomicAdd(&acc[3*NSLOT + slot], ms);
    atomicAdd(&acc[4*NSLOT + slot], ps);
  }
}

// ---------------------------------------------------------------------------
// Single wave of 64 threads: lane t owns slot t of each sum; butterfly-reduce.
// ---------------------------------------------------------------------------
__global__ void finalize_kernel(const double* __restrict__ acc, float* __restrict__ out){
  const int t = threadIdx.x;   // 64 threads
  double v[5];
  #pragma unroll
  for (int s = 0; s < 5; s++) v[s] = acc[s*NSLOT + t];
  #pragma unroll
  for (int o = 32; o > 0; o >>= 1)
    #pragma unroll
    for (int s = 0; s < 5; s++) v[s] += __shfl_down(v[s], o, 64);
  if (t == 0){
    const double inv = 1.0 / 8388608.0;      // mean over 8*1024*1024
    double grad   = v[0] * inv / 3.0;        // / len(bms)
    double smooth = v[1] * inv;
    double slope  = v[2] * inv;
    double freq   = (v[3] + 2.0 * v[4]) * inv;
    double total  = 2.0*grad + 1.5*freq + 3.0*smooth + 2.0*slope;
    out[0] = (float)total;
    out[1] = (float)grad;
    out[2] = (float)freq;
    out[3] = (float)smooth;
    out[4] = (float)slope;
  }
}

extern "C" void kernel_launch(void* const* d_in, const int* in_sizes, int n_in,
                              void* d_out, int out_size, void* d_ws, size_t ws_size,
                              hipStream_t stream){
  const float* pred = (const float*)d_in[0];
  const float* targ = (const float*)d_in[1];
  const float* mask = (const float*)d_in[2];
  double* acc = (double*)d_ws;
  float2* Z = (float2*)((char*)d_ws + 4096);
  const size_t zimg = (size_t)HW * HW * sizeof(float2);   // 8 MiB per image

  int cmax = 1;
  if (ws_size > 4096){
    size_t c = (ws_size - 4096) / zimg;
    if (c > 8) c = 8;
    if (c < 1) c = 1;
    cmax = (int)c;
  }

  zero_acc_kernel<<<2, 256, 0, stream>>>(acc);
  spatial_kernel<<<dim3(32, 32, 8), 256, 0, stream>>>(pred, targ, mask, acc);
  for (int i0 = 0; i0 < 8; i0 += cmax){
    int c = (8 - i0 < cmax) ? (8 - i0) : cmax;
    fft_rows_kernel<<<dim3(1024, c), 256, 0, stream>>>(pred, targ, Z, i0);
    transpose_kernel<<<dim3(32, 32, c), 256, 0, stream>>>(Z);
    fft_cols_reduce_kernel<<<dim3(513, c), 256, 0, stream>>>(Z, acc);
  }
  finalize_kernel<<<1, 64, 0, stream>>>(acc, (float*)d_out);
}